// Round 4
// baseline (586.067 us; speedup 1.0000x reference)
//
#include <hip/hip_runtime.h>
#include <hip/hip_bf16.h>

// ---------------------------------------------------------------------------
// Transformer block (B=8, N=1024, D=1024, H=16, HD=64, FF=4096), fp32 in/out.
// bf16 MFMA GEMMs, flash attention, fused epilogues.
// R4: QKV + fc1 on gemm256: faithful 256^2/BK=64/8-wave multi-phase schedule
// (T2+T3+T4+T5). Key fixes vs the failed R1 attempt: (a) >=3-phase
// issue-to-fence distance for every half-tile (vmcnt(6) = 3 halves in
// flight, template formula), (b) stage targets derived from dead-region
// analysis (no DMA into a region with pending reads), (c) balanced grids
// (384/512 blocks, 8-divisible). proj/fc2 stay on the R3 2-phase 128^2
// kernel (N=1024 grids don't fit 256^2).
// ---------------------------------------------------------------------------

typedef __attribute__((ext_vector_type(8))) short short8;
typedef __attribute__((ext_vector_type(4))) float floatx4;

__device__ __forceinline__ unsigned short f2bf(float f) {
  union { __hip_bfloat16 h; unsigned short u; } cv;
  cv.h = __float2bfloat16(f);
  return cv.u;
}

__device__ __forceinline__ float fast_exp2(float x) {
  return __builtin_amdgcn_exp2f(x);
}

__device__ __forceinline__ void async_ld16(const void* g, void* l) {
  __builtin_amdgcn_global_load_lds(
      (const __attribute__((address_space(1))) unsigned int*)g,
      (__attribute__((address_space(3))) unsigned int*)l, 16, 0, 0);
}

#define VMCNT(n) asm volatile("s_waitcnt vmcnt(" #n ")" ::: "memory")

// ---------------- fp32 -> bf16 weight conversion (4 elems/thread) ----------
__global__ __launch_bounds__(256) void cvt_bf16(const float* __restrict__ in,
                                                unsigned short* __restrict__ out) {
  const long i = ((long)blockIdx.x * 256 + threadIdx.x) * 4;
  const float4 v = *(const float4*)(in + i);
  ushort4 o;
  o.x = f2bf(v.x); o.y = f2bf(v.y); o.z = f2bf(v.z); o.w = f2bf(v.w);
  *(ushort4*)(out + i) = o;
}

// ---------------- LayerNorm: fp32 row -> bf16 row (one block per row) ------
__global__ __launch_bounds__(256) void ln_bf16(const float* __restrict__ x,
                                               const float* __restrict__ g,
                                               const float* __restrict__ b,
                                               unsigned short* __restrict__ out) {
  const int row = blockIdx.x;
  const int tid = threadIdx.x;
  const float4 v = ((const float4*)(x + (long)row * 1024))[tid];
  float s = v.x + v.y + v.z + v.w;
  float ss = v.x * v.x + v.y * v.y + v.z * v.z + v.w * v.w;
#pragma unroll
  for (int off = 1; off < 64; off <<= 1) {
    s += __shfl_xor(s, off);
    ss += __shfl_xor(ss, off);
  }
  __shared__ float red[8];
  const int wave = tid >> 6, lane = tid & 63;
  if (lane == 0) { red[wave] = s; red[4 + wave] = ss; }
  __syncthreads();
  if (tid == 0) {
    red[0] = red[0] + red[1] + red[2] + red[3];
    red[4] = red[4] + red[5] + red[6] + red[7];
  }
  __syncthreads();
  const float mu = red[0] * (1.f / 1024.f);
  const float var = red[4] * (1.f / 1024.f) - mu * mu;
  const float rstd = rsqrtf(var + 1e-5f);
  const int c = tid * 4;
  ushort4 o;
  o.x = f2bf((v.x - mu) * rstd * g[c + 0] + b[c + 0]);
  o.y = f2bf((v.y - mu) * rstd * g[c + 1] + b[c + 1]);
  o.z = f2bf((v.z - mu) * rstd * g[c + 2] + b[c + 2]);
  o.w = f2bf((v.w - mu) * rstd * g[c + 3] + b[c + 3]);
  ((ushort4*)(out + (long)row * 1024))[tid] = o;
}

// ---------------- shared epilogue ------------------------------------------
template <int MODE>
__device__ __forceinline__ void epi_store(
    long rr, long cg, float val, int N,
    const float* __restrict__ b0, const float* __restrict__ b1,
    const float* __restrict__ resid,
    void* __restrict__ out0, void* __restrict__ out1, void* __restrict__ out2) {
  if (MODE == 0) {
    const int which = (int)(cg >> 10);
    const int col = (int)(cg & 1023);
    const int bidx = (int)(rr >> 10), t = (int)(rr & 1023);
    const int head = col >> 6, hd = col & 63;
    const long bh = bidx * 16 + head;
    if (which == 0) {
      // fold softmax scale (1/8) AND log2(e) into Q -> attn uses raw exp2.
      ((unsigned short*)out0)[(bh * 1024 + t) * 64 + hd] =
          f2bf((val + b0[col]) * 0.1803368801111244f);
    } else if (which == 1) {
      ((unsigned short*)out1)[(bh * 1024 + t) * 64 + hd] = f2bf(val);
    } else {
      ((unsigned short*)out2)[(bh * 64 + hd) * 1024 + t] = f2bf(val + b1[col]);
    }
  } else if (MODE == 1) {
    const long idx = rr * N + cg;
    ((float*)out0)[idx] = resid[idx] + val + b0[cg];
  } else {
    const float u = val + b0[cg];
    const float gl = 0.5f * u * (1.0f + erff(u * 0.70710678118f));
    ((unsigned short*)out0)[rr * N + cg] = f2bf(gl);
  }
}

// ---------------- 128^2 GEMM (2-phase, BK=64) — proj / fc2 -----------------
#define BM 128
#define BN 128

template <int MODE>
__global__ __launch_bounds__(256) void gemm_bt(
    const unsigned short* __restrict__ A, const unsigned short* __restrict__ B,
    int M, int N, int Kd,
    const float* __restrict__ b0, const float* __restrict__ b1,
    const float* __restrict__ resid,
    void* __restrict__ out0, void* __restrict__ out1, void* __restrict__ out2) {
  __shared__ unsigned short lA[2][2][BM * 32];   // [buf][k32-sub][tile]
  __shared__ unsigned short lB[2][2][BN * 32];
  const int tid = threadIdx.x;
  const int wave = tid >> 6, lane = tid & 63;
  const int l16 = lane & 15, quad = lane >> 4;
  const int wr = wave >> 1, wc = wave & 1;
  const int bid = blockIdx.x;
  const int xcd = bid & 7;
  const int s = bid >> 3;
  const long m0 = (long)(xcd * 8 + (s & 7)) * BM;
  const long n0 = (long)(s >> 3) * BN;

  const int row = tid >> 2;
  const int kc = (tid & 3) ^ ((row >> 1) & 3);  // swizzled granule column
  const unsigned short* aSrc = A + (m0 + row) * Kd + kc * 8;
  const unsigned short* bSrc = B + (n0 + row) * Kd + kc * 8;
  const int ldsOff0 = wave * 1024;
  const int ldsOff1 = wave * 1024 + 4096;

  floatx4 acc[4][4];
#pragma unroll
  for (int i = 0; i < 4; i++)
#pragma unroll
    for (int j = 0; j < 4; j++) acc[i][j] = (floatx4){0.f, 0.f, 0.f, 0.f};

#pragma unroll
  for (int sb = 0; sb < 2; sb++) {
    async_ld16(aSrc + sb * 32, (char*)&lA[0][sb][0] + ldsOff0);
    async_ld16(aSrc + 64 * Kd + sb * 32, (char*)&lA[0][sb][0] + ldsOff1);
    async_ld16(bSrc + sb * 32, (char*)&lB[0][sb][0] + ldsOff0);
    async_ld16(bSrc + 64 * Kd + sb * 32, (char*)&lB[0][sb][0] + ldsOff1);
  }

  const int sw = ((l16 >> 1) & 3);

  for (int k0 = 0; k0 < Kd; k0 += 64) {
    const int buf = (k0 >> 6) & 1;
    __syncthreads();
    const int kn = k0 + 64;
    if (kn < Kd) {
#pragma unroll
      for (int sb = 0; sb < 2; sb++) {
        async_ld16(aSrc + kn + sb * 32, (char*)&lA[buf ^ 1][sb][0] + ldsOff0);
        async_ld16(aSrc + 64 * Kd + kn + sb * 32,
                   (char*)&lA[buf ^ 1][sb][0] + ldsOff1);
        async_ld16(bSrc + kn + sb * 32, (char*)&lB[buf ^ 1][sb][0] + ldsOff0);
        async_ld16(bSrc + 64 * Kd + kn + sb * 32,
                   (char*)&lB[buf ^ 1][sb][0] + ldsOff1);
      }
    }
#pragma unroll
    for (int sb = 0; sb < 2; sb++) {
      short8 af[4], bfv[4];
#pragma unroll
      for (int mi = 0; mi < 4; mi++) {
        const int r = wr * 64 + mi * 16 + l16;
        af[mi] = *(const short8*)(&lA[buf][sb][(r * 4 + (quad ^ sw)) * 8]);
      }
#pragma unroll
      for (int ni = 0; ni < 4; ni++) {
        const int r = wc * 64 + ni * 16 + l16;
        bfv[ni] = *(const short8*)(&lB[buf][sb][(r * 4 + (quad ^ sw)) * 8]);
      }
#pragma unroll
      for (int mi = 0; mi < 4; mi++)
#pragma unroll
        for (int ni = 0; ni < 4; ni++)
          acc[mi][ni] = __builtin_amdgcn_mfma_f32_16x16x32_bf16(
              af[mi], bfv[ni], acc[mi][ni], 0, 0, 0);
    }
  }

#pragma unroll
  for (int mi = 0; mi < 4; mi++) {
    const long rbase = m0 + wr * 64 + mi * 16 + quad * 4;
#pragma unroll
    for (int ni = 0; ni < 4; ni++) {
      const long cg = n0 + wc * 64 + ni * 16 + l16;
#pragma unroll
      for (int reg = 0; reg < 4; reg++)
        epi_store<MODE>(rbase + reg, cg, acc[mi][ni][reg], N, b0, b1, resid,
                        out0, out1, out2);
    }
  }
  (void)M;
}

// ---------------- 256^2 GEMM, 8 waves, BK=64, 4-phase deep pipeline --------
// Faithful port of the verified 256^2 multi-phase schedule. 8 waves as
// 2M x 4N (wave tile 128x64, acc 8x4). LDS = 2 buf x 4 halves x 2 k-subs x
// 8 KB = 128 KiB. Half-tile = 128 rows x 64 k = 2 global_load_lds per
// thread (512 thr x 16 B = 8 KB sub-tile). Sub-tile granule swizzle is
// byte-identical to gemm_bt's (measured-zero conflicts).
//
// Phases per K-tile t (C-quadrant (qm,qn)): p0=(0,0) p1=(0,1) p2=(1,1)
// p3=(1,0); 16 MFMA each. Reads: p0: A-quad0 (8) + B ni01 (4); p1: B ni23
// (4); p2: A-quad1 (8); p3: none (regs held).
// Dead regions: A halves after p2, B halves after p1 -> stage schedule:
//   p0: T(t+1).A1 -> other buf (region dead since (t-1).p2)
//   p2: T(t+2).B0 -> this buf (B0 dead after p1)
//   p3: T(t+2).B1 + T(t+2).A0 -> this buf (dead after p1/p2)
// Fence: ONE vmcnt(6) per K-tile at p3 (3 halves = 6 loads in flight);
// every half of T(t+1) was issued >=3 phases before its fence. Tail: when
// t+2 >= NT the fence drains to vmcnt(0). Requires NT >= 3 (NT=16 here).
template <int MODE>
__global__ __launch_bounds__(512, 2) void gemm256(
    const unsigned short* __restrict__ A, const unsigned short* __restrict__ B,
    int M, int N, int Kd,
    const float* __restrict__ b0, const float* __restrict__ b1,
    const float* __restrict__ resid,
    void* __restrict__ out0, void* __restrict__ out1, void* __restrict__ out2) {
  // halves: 0 = A rows 0-127, 1 = A rows 128-255, 2 = B rows 0-127,
  //         3 = B rows 128-255; each half = 2 k-sub-tiles of [128 rows][32 k]
  __shared__ __align__(16) unsigned short lds[2][4][2][4096];
  const int tid = threadIdx.x;
  const int wave = tid >> 6, lane = tid & 63;
  const int l16 = lane & 15, quad = lane >> 4;
  const int wr = wave >> 2, wc = wave & 3;   // 2M x 4N wave grid
  const int bid = blockIdx.x;
  const int xcd = bid & 7, s = bid >> 3;
  const long m0 = (long)(xcd * 4 + (s & 3)) * 256;
  const long n0 = (long)(s >> 2) * 256;
  const int NT = Kd >> 6;

  // staging: thread stages granule tid of each 8 KB sub-tile; swizzle folded
  // into the global column (LDS side of global_load_lds is lane-contiguous)
  const int srow = tid >> 2;                       // 0..127
  const int skc = (tid & 3) ^ ((srow >> 1) & 3);   // swizzled granule col
  const unsigned short* aS = A + (m0 + srow) * Kd + skc * 8;
  const unsigned short* bS = B + (n0 + srow) * Kd + skc * 8;
  const unsigned short* aS1 = aS + 128 * (long)Kd;
  const unsigned short* bS1 = bS + 128 * (long)Kd;
  const int wvOff = wave * 1024;

#define STG(half, src, t, bp)                                                \
  do {                                                                       \
    async_ld16((src) + ((long)(t) << 6),                                     \
               (char*)&lds[bp][half][0][0] + wvOff);                         \
    async_ld16((src) + ((long)(t) << 6) + 32,                                \
               (char*)&lds[bp][half][1][0] + wvOff);                         \
  } while (0)

  floatx4 acc[8][4];
#pragma unroll
  for (int i = 0; i < 8; i++)
#pragma unroll
    for (int j = 0; j < 4; j++) acc[i][j] = (floatx4){0.f, 0.f, 0.f, 0.f};

  short8 af[4][2];   // current m-quadrant: 4 mi x 2 k-slices
  short8 bf[4][2];   // all 4 ni x 2 k-slices (held across the K-tile)
  const int sw = (l16 >> 1) & 3;

#define RDA(qm)                                                              \
  _Pragma("unroll") for (int mi = 0; mi < 4; mi++) {                         \
    const int r = (qm)*64 + mi * 16 + l16;                                   \
    _Pragma("unroll") for (int kk = 0; kk < 2; kk++)                         \
        af[mi][kk] = *(const short8*)(                                       \
            &lds[buf][wr][kk][(r * 4 + (quad ^ sw)) * 8]);                   \
  }
#define RDB(pair)                                                            \
  _Pragma("unroll") for (int j = 0; j < 2; j++) {                            \
    const int ni = (pair)*2 + j;                                             \
    const int r = (wc & 1) * 64 + ni * 16 + l16;                             \
    _Pragma("unroll") for (int kk = 0; kk < 2; kk++)                         \
        bf[ni][kk] = *(const short8*)(                                       \
            &lds[buf][2 + (wc >> 1)][kk][(r * 4 + (quad ^ sw)) * 8]);        \
  }
#define MFMA_Q(qm, qn)                                                       \
  __builtin_amdgcn_s_setprio(1);                                             \
  _Pragma("unroll") for (int mi = 0; mi < 4; mi++) {                         \
    _Pragma("unroll") for (int j = 0; j < 2; j++) {                          \
      floatx4 c_ = acc[(qm)*4 + mi][(qn)*2 + j];                             \
      c_ = __builtin_amdgcn_mfma_f32_16x16x32_bf16(af[mi][0],                \
                                                   bf[(qn)*2 + j][0], c_,    \
                                                   0, 0, 0);                 \
      c_ = __builtin_amdgcn_mfma_f32_16x16x32_bf16(af[mi][1],                \
                                                   bf[(qn)*2 + j][1], c_,    \
                                                   0, 0, 0);                 \
      acc[(qm)*4 + mi][(qn)*2 + j] = c_;                                     \
    }                                                                        \
  }                                                                          \
  __builtin_amdgcn_s_setprio(0);
#define LGKM0                                                                \
  asm volatile("s_waitcnt lgkmcnt(0)" ::: "memory");                         \
  __builtin_amdgcn_sched_barrier(0);

  // prologue: T0 complete (8 loads) + T1.{B0,B1,A0} (6 loads, FIFO order
  // matching the steady-state invariant)
  STG(0, aS, 0, 0); STG(1, aS1, 0, 0); STG(2, bS, 0, 0); STG(3, bS1, 0, 0);
  STG(2, bS, 1, 1); STG(3, bS1, 1, 1); STG(0, aS, 1, 1);
  VMCNT(6);  // T0 landed; T1.{B0,B1,A0} in flight
  __builtin_amdgcn_s_barrier();

  for (int t = 0; t < NT; ++t) {
    const int buf = t & 1, nxt = buf ^ 1;
    // ---- p0: quadrant (0,0)
    RDA(0);
    RDB(0);
    if (t + 1 < NT) STG(1, aS1, t + 1, nxt);
    __builtin_amdgcn_s_barrier();
    LGKM0;
    MFMA_Q(0, 0);
    __builtin_amdgcn_s_barrier();
    // ---- p1: quadrant (0,1)
    RDB(1);
    __builtin_amdgcn_s_barrier();
    LGKM0;
    MFMA_Q(0, 1);
    __builtin_amdgcn_s_barrier();
    // ---- p2: quadrant (1,1)
    RDA(1);
    if (t + 2 < NT) STG(2, bS, t + 2, buf);
    __builtin_amdgcn_s_barrier();
    LGKM0;
    MFMA_Q(1, 1);
    __builtin_amdgcn_s_barrier();
    // ---- p3: quadrant (1,0) — af from p2, bf ni01 from p0 (regs held)
    if (t + 2 < NT) { STG(3, bS1, t + 2, buf); STG(0, aS, t + 2, buf); }
    __builtin_amdgcn_s_barrier();
    MFMA_Q(1, 0);
    if (t + 2 < NT) { VMCNT(6); } else { VMCNT(0); }
    __builtin_amdgcn_s_barrier();
  }

  // epilogue
#pragma unroll
  for (int mi2 = 0; mi2 < 8; mi2++) {
    const long rbase = m0 + wr * 128 + mi2 * 16 + quad * 4;
#pragma unroll
    for (int nj = 0; nj < 4; nj++) {
      const long cg = n0 + wc * 64 + nj * 16 + l16;
#pragma unroll
      for (int reg = 0; reg < 4; reg++)
        epi_store<MODE>(rbase + reg, cg, acc[mi2][nj][reg], N, b0, b1, resid,
                        out0, out1, out2);
    }
  }
  (void)M;
#undef STG
#undef RDA
#undef RDB
#undef MFMA_Q
#undef LGKM0
}

// ---------------- Flash attention, LDS-shared K/V --------------------------
__global__ __launch_bounds__(256) void attn(const unsigned short* __restrict__ Q,
                                            const unsigned short* __restrict__ Kc,
                                            const unsigned short* __restrict__ Vt,
                                            unsigned short* __restrict__ O) {
  __shared__ unsigned short lK[2][2048];
  __shared__ unsigned short lV[2][2048];
  __shared__ float P[4][2][16][34];
  const int tid = threadIdx.x;
  const int wave = tid >> 6, lane = tid & 63;
  const int l16 = lane & 15, quad = lane >> 4;
  const int bid = blockIdx.x;
  const int xcd = bid & 7;
  const int sl = bid >> 3;
  const int bh = xcd * 16 + (sl & 15);
  const int q0 = (sl >> 4) * 128 + wave * 32;
  const unsigned short* Qb = Q + ((long)bh * 1024 + q0) * 64;
  const unsigned short* Kb = Kc + (long)bh * 65536;
  const unsigned short* Vb = Vt + (long)bh * 65536;

  short8 qf[2][2];
#pragma unroll
  for (int t = 0; t < 2; t++)
#pragma unroll
    for (int h = 0; h < 2; h++)
      qf[t][h] = *(const short8*)(Qb + (t * 16 + l16) * 64 + h * 32 + quad * 8);

  const int kr = tid >> 3;
  const int kc = (tid & 7) ^ (kr & 7);
  const unsigned short* kSrc = Kb + kr * 64 + kc * 8;
  const int vr = tid >> 2;
  const int vc = (tid & 3) ^ (vr & 3) ^ ((vr >> 2) & 3);
  const unsigned short* vSrc = Vb + vr * 1024 + vc * 8;

  floatx4 oacc[2][4];
#pragma unroll
  for (int t = 0; t < 2; t++)
#pragma unroll
    for (int u = 0; u < 4; u++) oacc[t][u] = (floatx4){0.f, 0.f, 0.f, 0.f};
  float lrun[2][4] = {{0.f, 0.f, 0.f, 0.f}, {0.f, 0.f, 0.f, 0.f}};

  async_ld16(kSrc, (char*)&lK[0][0] + wave * 1024);
  async_ld16(vSrc, (char*)&lV[0][0] + wave * 1024);

  const int vca = quad ^ (l16 & 3) ^ ((l16 >> 2) & 3);

  for (int ks = 0; ks < 1024; ks += 32) {
    const int buf = (ks >> 5) & 1;
    __syncthreads();
    const int kn = ks + 32;
    if (kn < 1024) {
      async_ld16(kSrc + kn * 64, (char*)&lK[buf ^ 1][0] + wave * 1024);
      async_ld16(vSrc + kn,      (char*)&lV[buf ^ 1][0] + wave * 1024);
    }
    short8 kf[2][2];
#pragma unroll
    for (int i = 0; i < 2; i++)
#pragma unroll
      for (int h = 0; h < 2; h++) {
        const int gr = (i * 16 + l16) * 8 + ((h * 4 + quad) ^ (l16 & 7));
        kf[i][h] = *(const short8*)(&lK[buf][gr * 8]);
      }
    floatx4 sres[2][2];
#pragma unroll
    for (int t = 0; t < 2; t++)
#pragma unroll
      for (int i = 0; i < 2; i++) {
        const floatx4 z = {0.f, 0.f, 0.f, 0.f};
        floatx4 a = __builtin_amdgcn_mfma_f32_16x16x32_bf16(qf[t][0], kf[i][0], z, 0, 0, 0);
        sres[t][i] = __builtin_amdgcn_mfma_f32_16x16x32_bf16(qf[t][1], kf[i][1], a, 0, 0, 0);
      }
#pragma unroll
    for (int t = 0; t < 2; t++)
#pragma unroll
      for (int r = 0; r < 4; r++) {
        const float p0 = fast_exp2(sres[t][0][r]);
        const float p1 = fast_exp2(sres[t][1][r]);
        lrun[t][r] += p0 + p1;
        P[wave][t][quad * 4 + r][l16] = p0;
        P[wave][t][quad * 4 + r][16 + l16] = p1;
      }
    short8 vf[4];
#pragma unroll
    for (int u = 0; u < 4; u++)
      vf[u] = *(const short8*)(&lV[buf][((u * 16 + l16) * 4 + vca) * 8]);
    short8 pf[2];
#pragma unroll
    for (int t = 0; t < 2; t++) {
      const float* pr = &P[wave][t][l16][quad * 8];
      const floatx4 pa = *(const floatx4*)pr;
      const floatx4 pb = *(const floatx4*)(pr + 4);
      pf[t][0] = (short)f2bf(pa[0]); pf[t][1] = (short)f2bf(pa[1]);
      pf[t][2] = (short)f2bf(pa[2]); pf[t][3] = (short)f2bf(pa[3]);
      pf[t][4] = (short)f2bf(pb[0]); pf[t][5] = (short)f2bf(pb[1]);
      pf[t][6] = (short)f2bf(pb[2]); pf[t][7] = (short)f2bf(pb[3]);
    }
#pragma unroll
    for (int t = 0; t < 2; t++)
#pragma unroll
      for (int u = 0; u < 4; u++)
        oacc[t][u] = __builtin_amdgcn_mfma_f32_16x16x32_bf16(pf[t], vf[u], oacc[t][u], 0, 0, 0);
  }

  const int b = bh >> 4, h = bh & 15;
#pragma unroll
  for (int t = 0; t < 2; t++) {
#pragma unroll
    for (int r = 0; r < 4; r++) {
      float lr = lrun[t][r];
      lr += __shfl_xor(lr, 1);
      lr += __shfl_xor(lr, 2);
      lr += __shfl_xor(lr, 4);
      lr += __shfl_xor(lr, 8);
      const float linv = 1.0f / lr;
#pragma unroll
      for (int u = 0; u < 4; u++) {
        O[((long)b * 1024 + q0 + t * 16 + quad * 4 + r) * 1024 + h * 64 + u * 16 + l16] =
            f2bf(oacc[t][u][r] * linv);
      }
    }
  }
}

// ---------------------------------------------------------------------------
extern "C" void kernel_launch(void* const* d_in, const int* in_sizes, int n_in,
                              void* d_out, int out_size, void* d_ws, size_t ws_size,
                              hipStream_t stream) {
  const float* x      = (const float*)d_in[0];
  const float* ln1_g  = (const float*)d_in[1];
  const float* ln1_b  = (const float*)d_in[2];
  const float* ln2_g  = (const float*)d_in[3];
  const float* ln2_b  = (const float*)d_in[4];
  const float* qkv_w  = (const float*)d_in[5];
  const float* q_bias = (const float*)d_in[6];
  const float* v_bias = (const float*)d_in[7];
  const float* proj_w = (const float*)d_in[8];
  const float* proj_b = (const float*)d_in[9];
  const float* fc1_w  = (const float*)d_in[10];
  const float* fc1_b  = (const float*)d_in[11];
  const float* fc2_w  = (const float*)d_in[12];
  const float* fc2_b  = (const float*)d_in[13];
  float* out = (float*)d_out;

  char* ws = (char*)d_ws;
  unsigned short* Wqkv  = (unsigned short*)(ws);              //  6 MB
  unsigned short* Wproj = (unsigned short*)(ws + 6291456);    //  2 MB
  unsigned short* Wfc1  = (unsigned short*)(ws + 8388608);    //  8 MB
  unsigned short* Wfc2  = (unsigned short*)(ws + 16777216);   //  8 MB
  float*          X1    = (float*)        (ws + 25165824);    // 32 MB fp32
  unsigned short* Hbuf  = (unsigned short*)(ws + 58720256);   // 16 MB
  unsigned short* Qbuf  = (unsigned short*)(ws + 75497472);   // 16 MB
  unsigned short* Kbuf  = (unsigned short*)(ws + 92274688);   // 16 MB
  unsigned short* Vtbuf = (unsigned short*)(ws + 109051904);  // 16 MB
  unsigned short* Obuf  = (unsigned short*)(ws + 125829120);  // 16 MB
  unsigned short* ACT   = Qbuf;  // reuse dead Q/K/Vt/O region: 64 MB

  // weights -> bf16
  cvt_bf16<<<3072 * 1024 / 1024, 256, 0, stream>>>(qkv_w, Wqkv);
  cvt_bf16<<<1024 * 1024 / 1024, 256, 0, stream>>>(proj_w, Wproj);
  cvt_bf16<<<4096 * 1024 / 1024, 256, 0, stream>>>(fc1_w, Wfc1);
  cvt_bf16<<<4096 * 1024 / 1024, 256, 0, stream>>>(fc2_w, Wfc2);

  // LN1
  ln_bf16<<<8192, 256, 0, stream>>>(x, ln1_g, ln1_b, Hbuf);
  // QKV gemm + scatter: 256^2 tiles, 32 m x 12 n = 384 blocks
  gemm256<0><<<384, 512, 0, stream>>>(Hbuf, Wqkv, 8192, 3072, 1024,
                                      q_bias, v_bias, nullptr,
                                      Qbuf, Kbuf, Vtbuf);
  // attention
  attn<<<1024, 256, 0, stream>>>(Qbuf, Kbuf, Vtbuf, Obuf);
  // proj + residual -> X1 (fp32)
  gemm_bt<1><<<8 * 64, 256, 0, stream>>>(Obuf, Wproj, 8192, 1024, 1024,
                                         proj_b, nullptr, x,
                                         X1, nullptr, nullptr);
  // LN2
  ln_bf16<<<8192, 256, 0, stream>>>(X1, ln2_g, ln2_b, Hbuf);
  // fc1 + gelu -> ACT (bf16): 32 x 16 = 512 blocks
  gemm256<2><<<512, 512, 0, stream>>>(Hbuf, Wfc1, 8192, 4096, 1024,
                                      fc1_b, nullptr, nullptr,
                                      ACT, nullptr, nullptr);
  // fc2 + residual -> out (fp32)
  gemm_bt<1><<<8 * 64, 256, 0, stream>>>(ACT, Wfc2, 8192, 1024, 4096,
                                         fc2_b, nullptr, X1,
                                         out, nullptr, nullptr);
  (void)in_sizes; (void)n_in; (void)out_size; (void)ws_size;
}

// Round 7
// 557.161 us; speedup vs baseline: 1.0519x; 1.0519x over previous
//
#include <hip/hip_runtime.h>
#include <hip/hip_bf16.h>

// ---------------------------------------------------------------------------
// Transformer block (B=8, N=1024, D=1024, H=16, HD=64, FF=4096), fp32 in/out.
// bf16 MFMA GEMMs, flash attention (LDS-shared K/V, no-shift softmax),
// fused epilogues.
// R7 (base = R3, fusion experiments abandoned):
//  (1) gemm_bt: 3-buffer BK=32 counted-vmcnt pipeline. Per iter:
//      vmcnt(4) [tail 0] -> s_barrier (raw, no drain) -> stage buf j+2 ->
//      read buf j -> 16 MFMA. Keeps 4-8 DMA loads in flight across
//      barriers (T4); 48 KiB LDS -> 3 blocks/CU (was 2). Race analysis:
//      per-wave vmcnt(4) pre-barrier forces buf_j resident collectively;
//      buf_{j+2}=buf_{j-1} staged only after barrier_j, by which time all
//      waves' reads of it were consumed (lgkmcnt before their MFMAs,
//      pinned by sched_barrier(0) pairs).
//  (2) QKV epilogue: Vt scatter packed 4x (4 acc regs = 4 consecutive t ->
//      one 8B store). QKV measured 450 TF vs fc1 598 from 2B/lane scatter.
// ---------------------------------------------------------------------------

typedef __attribute__((ext_vector_type(8))) short short8;
typedef __attribute__((ext_vector_type(4))) float floatx4;

__device__ __forceinline__ unsigned short f2bf(float f) {
  union { __hip_bfloat16 h; unsigned short u; } cv;
  cv.h = __float2bfloat16(f);
  return cv.u;
}

// 2^x via the native v_exp_f32 instruction (avoid glibc __exp2f macro clash)
__device__ __forceinline__ float fast_exp2(float x) {
  return __builtin_amdgcn_exp2f(x);
}

__device__ __forceinline__ void async_ld16(const void* g, void* l) {
  __builtin_amdgcn_global_load_lds(
      (const __attribute__((address_space(1))) unsigned int*)g,
      (__attribute__((address_space(3))) unsigned int*)l, 16, 0, 0);
}

#define VMCNT(n) asm volatile("s_waitcnt vmcnt(" #n ")" ::: "memory")

// ---------------- fp32 -> bf16 weight conversion (4 elems/thread) ----------
__global__ __launch_bounds__(256) void cvt_bf16(const float* __restrict__ in,
                                                unsigned short* __restrict__ out) {
  const long i = ((long)blockIdx.x * 256 + threadIdx.x) * 4;
  const float4 v = *(const float4*)(in + i);
  ushort4 o;
  o.x = f2bf(v.x); o.y = f2bf(v.y); o.z = f2bf(v.z); o.w = f2bf(v.w);
  *(ushort4*)(out + i) = o;
}

// ---------------- LayerNorm: fp32 row -> bf16 row (one block per row) ------
__global__ __launch_bounds__(256) void ln_bf16(const float* __restrict__ x,
                                               const float* __restrict__ g,
                                               const float* __restrict__ b,
                                               unsigned short* __restrict__ out) {
  const int row = blockIdx.x;
  const int tid = threadIdx.x;
  const float4 v = ((const float4*)(x + (long)row * 1024))[tid];
  float s = v.x + v.y + v.z + v.w;
  float ss = v.x * v.x + v.y * v.y + v.z * v.z + v.w * v.w;
#pragma unroll
  for (int off = 1; off < 64; off <<= 1) {
    s += __shfl_xor(s, off);
    ss += __shfl_xor(ss, off);
  }
  __shared__ float red[8];
  const int wave = tid >> 6, lane = tid & 63;
  if (lane == 0) { red[wave] = s; red[4 + wave] = ss; }
  __syncthreads();
  if (tid == 0) {
    red[0] = red[0] + red[1] + red[2] + red[3];
    red[4] = red[4] + red[5] + red[6] + red[7];
  }
  __syncthreads();
  const float mu = red[0] * (1.f / 1024.f);
  const float var = red[4] * (1.f / 1024.f) - mu * mu;
  const float rstd = rsqrtf(var + 1e-5f);
  const int c = tid * 4;
  ushort4 o;
  o.x = f2bf((v.x - mu) * rstd * g[c + 0] + b[c + 0]);
  o.y = f2bf((v.y - mu) * rstd * g[c + 1] + b[c + 1]);
  o.z = f2bf((v.z - mu) * rstd * g[c + 2] + b[c + 2]);
  o.w = f2bf((v.w - mu) * rstd * g[c + 3] + b[c + 3]);
  ((ushort4*)(out + (long)row * 1024))[tid] = o;
}

// ---------------- GEMM: C[M,N] = A[M,K] @ B[N,K]^T, fused epilogues --------
// 1-D grid of (N/128)*64 blocks. XCD-aware decode (dispatch round-robin:
// xcd = bid & 7): each XCD owns 8 contiguous m-tiles (2 MB A-stripe,
// L2-resident) and sweeps n-tiles; co-resident blocks share B k-slices
// through L2.
// Triple-buffered LDS staging with counted vmcnt: buffer j's 4 DMA loads
// are issued at iter j-2 and fenced by vmcnt(4) at iter j's barrier, so
// 4-8 loads stay in flight across every barrier (no full drain).
// LDS granule swizzle: granule (row, kc) stored at (row, kc^((row>>1)&3))
// -- applied on the GLOBAL source address since global_load_lds's LDS side
// is lane-contiguous. Fragment ds_read_b128 then hits banks in {r, r+8}
// pairs = 2-way conflicts only (free; measured 0).
// MODE 0: QKV scatter  (out0=Q [bh,n,hd] *scale*log2e+qb, out1=K [bh,n,hd],
//                       out2=Vt [bh,hd,n] +vb, packed 4-t stores)
// MODE 1: fp32 out = resid + acc + bias   (proj / fc2)
// MODE 2: bf16 out = gelu(acc + bias)     (fc1)
#define BM 128
#define BN 128

template <int MODE>
__global__ __launch_bounds__(256) void gemm_bt(
    const unsigned short* __restrict__ A, const unsigned short* __restrict__ B,
    int M, int N, int Kd,
    const float* __restrict__ b0, const float* __restrict__ b1,
    const float* __restrict__ resid,
    void* __restrict__ out0, void* __restrict__ out1, void* __restrict__ out2) {
  __shared__ unsigned short lA[3][BM * 32];   // 3 x 8 KB
  __shared__ unsigned short lB[3][BN * 32];   // 3 x 8 KB
  const int tid = threadIdx.x;
  const int wave = tid >> 6, lane = tid & 63;
  const int l16 = lane & 15, quad = lane >> 4;
  const int wr = wave >> 1, wc = wave & 1;
  // XCD-striped decode (M/128 == 64 rows of tiles; 8 per XCD)
  const int bid = blockIdx.x;
  const int xcd = bid & 7;
  const int s = bid >> 3;
  const long m0 = (long)(xcd * 8 + (s & 7)) * BM;
  const long n0 = (long)(s >> 3) * BN;

  // staging addresses: thread stages granule tid (+256) of each tile,
  // with the bank-swizzle folded into the global column
  const int row = tid >> 2;
  const int kc = (tid & 3) ^ ((row >> 1) & 3);  // swizzled granule column
  const unsigned short* aSrc = A + (m0 + row) * Kd + kc * 8;
  const unsigned short* bSrc = B + (n0 + row) * Kd + kc * 8;
  // note: ((row+64)>>1)&3 == ((row>>1)&3), so the +64-row granule reuses kc
  const int ldsOff0 = wave * 1024;            // bytes: (wave*64)*16
  const int ldsOff1 = wave * 1024 + 4096;     // bytes: (+256 granules)

  floatx4 acc[4][4];
#pragma unroll
  for (int i = 0; i < 4; i++)
#pragma unroll
    for (int j = 0; j < 4; j++) acc[i][j] = (floatx4){0.f, 0.f, 0.f, 0.f};

  // prologue: stage buffers 0 and 1 (k=0 and k=32); 8 loads outstanding
#pragma unroll
  for (int bp = 0; bp < 2; bp++) {
    const int kk = bp * 32;
    async_ld16(aSrc + kk, (char*)&lA[bp][0] + ldsOff0);
    async_ld16(aSrc + 64 * Kd + kk, (char*)&lA[bp][0] + ldsOff1);
    async_ld16(bSrc + kk, (char*)&lB[bp][0] + ldsOff0);
    async_ld16(bSrc + 64 * Kd + kk, (char*)&lB[bp][0] + ldsOff1);
  }

  // per-lane swizzled read granules (fragment row = base + l16)
  const int sw = ((l16 >> 1) & 3);  // (row>>1)&3 for row = (multiple of 16)+l16

  int buf = 0;
  for (int k0 = 0; k0 < Kd; k0 += 32) {
    // fence: my older-than-4 loads (= buffer `buf`) have landed; all waves
    // do this before the barrier, so collectively `buf` is fully resident.
    if (k0 + 32 < Kd) { VMCNT(4); } else { VMCNT(0); }
    __builtin_amdgcn_sched_barrier(0);   // nothing crosses (pins MFMAs above)
    __builtin_amdgcn_s_barrier();
    __builtin_amdgcn_sched_barrier(0);   // nothing crosses (pins reads below)
    const int kn = k0 + 64;
    if (kn < Kd) {
      const int bp = (buf + 2 >= 3) ? buf - 1 : buf + 2;  // (buf+2)%3
      async_ld16(aSrc + kn, (char*)&lA[bp][0] + ldsOff0);
      async_ld16(aSrc + 64 * Kd + kn, (char*)&lA[bp][0] + ldsOff1);
      async_ld16(bSrc + kn, (char*)&lB[bp][0] + ldsOff0);
      async_ld16(bSrc + 64 * Kd + kn, (char*)&lB[bp][0] + ldsOff1);
    }
    short8 af[4], bfv[4];
#pragma unroll
    for (int mi = 0; mi < 4; mi++) {
      const int r = wr * 64 + mi * 16 + l16;
      af[mi] = *(const short8*)(&lA[buf][(r * 4 + (quad ^ sw)) * 8]);
    }
#pragma unroll
    for (int ni = 0; ni < 4; ni++) {
      const int r = wc * 64 + ni * 16 + l16;
      bfv[ni] = *(const short8*)(&lB[buf][(r * 4 + (quad ^ sw)) * 8]);
    }
#pragma unroll
    for (int mi = 0; mi < 4; mi++)
#pragma unroll
      for (int ni = 0; ni < 4; ni++)
        acc[mi][ni] = __builtin_amdgcn_mfma_f32_16x16x32_bf16(
            af[mi], bfv[ni], acc[mi][ni], 0, 0, 0);
    buf = (buf + 1 >= 3) ? 0 : buf + 1;
  }

#pragma unroll
  for (int mi = 0; mi < 4; mi++) {
    const long rbase = m0 + wr * 64 + mi * 16 + quad * 4;
#pragma unroll
    for (int ni = 0; ni < 4; ni++) {
      const long cg = n0 + wc * 64 + ni * 16 + l16;
      if (MODE == 0) {
        const int which = (int)(cg >> 10);
        const int col = (int)(cg & 1023);
        const int head = col >> 6, hd = col & 63;
        if (which == 2) {
          // Vt: the 4 acc regs are 4 CONSECUTIVE t -> one 8B packed store
          // (4x fewer L2 line-touches than the 2B scatter).
          const int bidx = (int)(rbase >> 10);
          const int t = (int)(rbase & 1023);
          const long bh = bidx * 16 + head;
          const float bv = b1[col];
          ushort4 pk;
          pk.x = f2bf(acc[mi][ni][0] + bv);
          pk.y = f2bf(acc[mi][ni][1] + bv);
          pk.z = f2bf(acc[mi][ni][2] + bv);
          pk.w = f2bf(acc[mi][ni][3] + bv);
          *(ushort4*)((unsigned short*)out2 + (bh * 64 + hd) * 1024 + t) = pk;
        } else {
#pragma unroll
          for (int reg = 0; reg < 4; reg++) {
            const long rr = rbase + reg;
            const float val = acc[mi][ni][reg];
            const int bidx = (int)(rr >> 10), t = (int)(rr & 1023);
            const long bh = bidx * 16 + head;
            if (which == 0) {
              // fold softmax scale (1/8) AND log2(e) into Q -> attn uses
              // raw exp2 (native v_exp_f32) with no shift.
              ((unsigned short*)out0)[(bh * 1024 + t) * 64 + hd] =
                  f2bf((val + b0[col]) * 0.1803368801111244f);
            } else {
              ((unsigned short*)out1)[(bh * 1024 + t) * 64 + hd] = f2bf(val);
            }
          }
        }
      } else {
#pragma unroll
        for (int reg = 0; reg < 4; reg++) {
          const long rr = rbase + reg;
          const float val = acc[mi][ni][reg];
          if (MODE == 1) {
            const long idx = rr * N + cg;
            ((float*)out0)[idx] = resid[idx] + val + b0[cg];
          } else {
            const float u = val + b0[cg];
            const float gl = 0.5f * u * (1.0f + erff(u * 0.70710678118f));
            ((unsigned short*)out0)[rr * N + cg] = f2bf(gl);
          }
        }
      }
    }
  }
  (void)M;
}

// ---------------- Flash attention, LDS-shared K/V (unchanged from R3) ------
// 1-D grid of 1024 blocks, XCD-striped: xcd = bid&7 owns 16 bh; all 8
// q-blocks of a bh land on one XCD so K/V k-slices are L2-shared. Block =
// 256 threads = 4 waves; each wave owns 32 Q rows; K/V tiles staged in LDS
// (global_load_lds, double-buffered, 1 barrier/iter). K granules (16B)
// XOR-swizzled on the GLOBAL side so ds_read_b128 fragment reads are
// <=2-way bank conflicted (free). Q pre-scaled by 0.125*log2e.
__global__ __launch_bounds__(256) void attn(const unsigned short* __restrict__ Q,
                                            const unsigned short* __restrict__ Kc,
                                            const unsigned short* __restrict__ Vt,
                                            unsigned short* __restrict__ O) {
  __shared__ unsigned short lK[2][2048];   // 4 KB per buffer: 32 kv x 64 hd
  __shared__ unsigned short lV[2][2048];   // 4 KB per buffer: 64 hd x 32 kv
  __shared__ float P[4][2][16][34];        // per-wave, per-Q-tile P slab
  const int tid = threadIdx.x;
  const int wave = tid >> 6, lane = tid & 63;
  const int l16 = lane & 15, quad = lane >> 4;
  const int bid = blockIdx.x;
  const int xcd = bid & 7;
  const int sl = bid >> 3;
  const int bh = xcd * 16 + (sl & 15);
  const int q0 = (sl >> 4) * 128 + wave * 32;
  const unsigned short* Qb = Q + ((long)bh * 1024 + q0) * 64;
  const unsigned short* Kb = Kc + (long)bh * 65536;
  const unsigned short* Vb = Vt + (long)bh * 65536;

  // Q fragments: 2 tiles x 2 k-halves
  short8 qf[2][2];
#pragma unroll
  for (int t = 0; t < 2; t++)
#pragma unroll
    for (int h = 0; h < 2; h++)
      qf[t][h] = *(const short8*)(Qb + (t * 16 + l16) * 64 + h * 32 + quad * 8);

  // staging source addresses (thread t stages LDS granule t of each tile)
  const int kr = tid >> 3;                                  // K row 0..31
  const int kc = (tid & 7) ^ (kr & 7);                      // swizzled col
  const unsigned short* kSrc = Kb + kr * 64 + kc * 8;
  const int vr = tid >> 2;                                  // Vt row 0..63
  const int vc = (tid & 3) ^ (vr & 3) ^ ((vr >> 2) & 3);    // swizzled col
  const unsigned short* vSrc = Vb + vr * 1024 + vc * 8;

  floatx4 oacc[2][4];
#pragma unroll
  for (int t = 0; t < 2; t++)
#pragma unroll
    for (int u = 0; u < 4; u++) oacc[t][u] = (floatx4){0.f, 0.f, 0.f, 0.f};
  float lrun[2][4] = {{0.f, 0.f, 0.f, 0.f}, {0.f, 0.f, 0.f, 0.f}};

  // prologue: stage buffer 0
  async_ld16(kSrc, (char*)&lK[0][0] + wave * 1024);
  async_ld16(vSrc, (char*)&lV[0][0] + wave * 1024);

  const int vca = quad ^ (l16 & 3) ^ ((l16 >> 2) & 3);  // V read swizzle

  for (int ks = 0; ks < 1024; ks += 32) {
    const int buf = (ks >> 5) & 1;
    __syncthreads();  // drains this buffer's staged loads (vmcnt(0))
    const int kn = ks + 32;
    if (kn < 1024) {
      async_ld16(kSrc + kn * 64, (char*)&lK[buf ^ 1][0] + wave * 1024);
      async_ld16(vSrc + kn,      (char*)&lV[buf ^ 1][0] + wave * 1024);
    }
    // K fragments (shared by both Q tiles)
    short8 kf[2][2];
#pragma unroll
    for (int i = 0; i < 2; i++)
#pragma unroll
      for (int h = 0; h < 2; h++) {
        const int gr = (i * 16 + l16) * 8 + ((h * 4 + quad) ^ (l16 & 7));
        kf[i][h] = *(const short8*)(&lK[buf][gr * 8]);
      }
    // QK^T
    floatx4 sres[2][2];
#pragma unroll
    for (int t = 0; t < 2; t++)
#pragma unroll
      for (int i = 0; i < 2; i++) {
        const floatx4 z = {0.f, 0.f, 0.f, 0.f};
        floatx4 a = __builtin_amdgcn_mfma_f32_16x16x32_bf16(qf[t][0], kf[i][0], z, 0, 0, 0);
        sres[t][i] = __builtin_amdgcn_mfma_f32_16x16x32_bf16(qf[t][1], kf[i][1], a, 0, 0, 0);
      }
    // softmax numerators + P slabs
#pragma unroll
    for (int t = 0; t < 2; t++)
#pragma unroll
      for (int r = 0; r < 4; r++) {
        const float p0 = fast_exp2(sres[t][0][r]);
        const float p1 = fast_exp2(sres[t][1][r]);
        lrun[t][r] += p0 + p1;
        P[wave][t][quad * 4 + r][l16] = p0;
        P[wave][t][quad * 4 + r][16 + l16] = p1;
      }
    // V fragments (shared by both Q tiles)
    short8 vf[4];
#pragma unroll
    for (int u = 0; u < 4; u++)
      vf[u] = *(const short8*)(&lV[buf][((u * 16 + l16) * 4 + vca) * 8]);
    // P: C-layout -> A-operand layout via private LDS slab (intra-wave)
    short8 pf[2];
#pragma unroll
    for (int t = 0; t < 2; t++) {
      const float* pr = &P[wave][t][l16][quad * 8];
      const floatx4 pa = *(const floatx4*)pr;
      const floatx4 pb = *(const floatx4*)(pr + 4);
      pf[t][0] = (short)f2bf(pa[0]); pf[t][1] = (short)f2bf(pa[1]);
      pf[t][2] = (short)f2bf(pa[2]); pf[t][3] = (short)f2bf(pa[3]);
      pf[t][4] = (short)f2bf(pb[0]); pf[t][5] = (short)f2bf(pb[1]);
      pf[t][6] = (short)f2bf(pb[2]); pf[t][7] = (short)f2bf(pb[3]);
    }
    // P @ V
#pragma unroll
    for (int t = 0; t < 2; t++)
#pragma unroll
      for (int u = 0; u < 4; u++)
        oacc[t][u] = __builtin_amdgcn_mfma_f32_16x16x32_bf16(pf[t], vf[u], oacc[t][u], 0, 0, 0);
  }

  // final denominator reduce across the 16 kv-lanes
  const int b = bh >> 4, h = bh & 15;
#pragma unroll
  for (int t = 0; t < 2; t++) {
#pragma unroll
    for (int r = 0; r < 4; r++) {
      float lr = lrun[t][r];
      lr += __shfl_xor(lr, 1);
      lr += __shfl_xor(lr, 2);
      lr += __shfl_xor(lr, 4);
      lr += __shfl_xor(lr, 8);
      const float linv = 1.0f / lr;
#pragma unroll
      for (int u = 0; u < 4; u++) {
        O[((long)b * 1024 + q0 + t * 16 + quad * 4 + r) * 1024 + h * 64 + u * 16 + l16] =
            f2bf(oacc[t][u][r] * linv);
      }
    }
  }
}

// ---------------------------------------------------------------------------
extern "C" void kernel_launch(void* const* d_in, const int* in_sizes, int n_in,
                              void* d_out, int out_size, void* d_ws, size_t ws_size,
                              hipStream_t stream) {
  const float* x      = (const float*)d_in[0];
  const float* ln1_g  = (const float*)d_in[1];
  const float* ln1_b  = (const float*)d_in[2];
  const float* ln2_g  = (const float*)d_in[3];
  const float* ln2_b  = (const float*)d_in[4];
  const float* qkv_w  = (const float*)d_in[5];
  const float* q_bias = (const float*)d_in[6];
  const float* v_bias = (const float*)d_in[7];
  const float* proj_w = (const float*)d_in[8];
  const float* proj_b = (const float*)d_in[9];
  const float* fc1_w  = (const float*)d_in[10];
  const float* fc1_b  = (const float*)d_in[11];
  const float* fc2_w  = (const float*)d_in[12];
  const float* fc2_b  = (const float*)d_in[13];
  float* out = (float*)d_out;

  char* ws = (char*)d_ws;
  unsigned short* Wqkv  = (unsigned short*)(ws);              //  6 MB
  unsigned short* Wproj = (unsigned short*)(ws + 6291456);    //  2 MB
  unsigned short* Wfc1  = (unsigned short*)(ws + 8388608);    //  8 MB
  unsigned short* Wfc2  = (unsigned short*)(ws + 16777216);   //  8 MB
  float*          X1    = (float*)        (ws + 25165824);    // 32 MB fp32
  unsigned short* Hbuf  = (unsigned short*)(ws + 58720256);   // 16 MB
  unsigned short* Qbuf  = (unsigned short*)(ws + 75497472);   // 16 MB
  unsigned short* Kbuf  = (unsigned short*)(ws + 92274688);   // 16 MB
  unsigned short* Vtbuf = (unsigned short*)(ws + 109051904);  // 16 MB
  unsigned short* Obuf  = (unsigned short*)(ws + 125829120);  // 16 MB
  unsigned short* ACT   = Qbuf;  // reuse dead Q/K/Vt/O region: 64 MB

  // weights -> bf16
  cvt_bf16<<<3072 * 1024 / 1024, 256, 0, stream>>>(qkv_w, Wqkv);
  cvt_bf16<<<1024 * 1024 / 1024, 256, 0, stream>>>(proj_w, Wproj);
  cvt_bf16<<<4096 * 1024 / 1024, 256, 0, stream>>>(fc1_w, Wfc1);
  cvt_bf16<<<4096 * 1024 / 1024, 256, 0, stream>>>(fc2_w, Wfc2);

  // LN1
  ln_bf16<<<8192, 256, 0, stream>>>(x, ln1_g, ln1_b, Hbuf);
  // QKV gemm + scatter (q scaled by 0.125*log2e, v -> transposed)
  gemm_bt<0><<<24 * 64, 256, 0, stream>>>(Hbuf, Wqkv, 8192, 3072, 1024,
                                          q_bias, v_bias, nullptr,
                                          Qbuf, Kbuf, Vtbuf);
  // attention
  attn<<<1024, 256, 0, stream>>>(Qbuf, Kbuf, Vtbuf, Obuf);
  // proj + residual -> X1 (fp32)
  gemm_bt<1><<<8 * 64, 256, 0, stream>>>(Obuf, Wproj, 8192, 1024, 1024,
                                         proj_b, nullptr, x,
                                         X1, nullptr, nullptr);
  // LN2
  ln_bf16<<<8192, 256, 0, stream>>>(X1, ln2_g, ln2_b, Hbuf);
  // fc1 + gelu -> ACT (bf16)
  gemm_bt<2><<<32 * 64, 256, 0, stream>>>(Hbuf, Wfc1, 8192, 4096, 1024,
                                          fc1_b, nullptr, nullptr,
                                          ACT, nullptr, nullptr);
  // fc2 + residual -> out (fp32)
  gemm_bt<1><<<8 * 64, 256, 0, stream>>>(ACT, Wfc2, 8192, 1024, 4096,
                                         fc2_b, nullptr, X1,
                                         out, nullptr, nullptr);
  (void)in_sizes; (void)n_in; (void)out_size; (void)ws_size;
}